// Round 1
// baseline (157.363 us; speedup 1.0000x reference)
//
#include <hip/hip_runtime.h>

typedef unsigned short u16;
typedef unsigned int u32;
typedef __attribute__((ext_vector_type(4))) float f32x4;
typedef __attribute__((ext_vector_type(8))) short bf16x8;
typedef __attribute__((ext_vector_type(8))) unsigned short u16x8;

#define SEQ   2048
#define NB    2
#define NH    8
#define HD    128
#define EMB   1024
#define WIN   128
#define MTOT  4096      // NB*SEQ
#define NQKV  3072
#define HSZ   (SEQ*HD)          // elements per (b,h) plane
#define QKVSZ (NB*NH*HSZ)       // 4194304 elements per q/k/v tensor

static __device__ __forceinline__ u16 f2bf(float f){
  u32 x = __builtin_bit_cast(u32, f);
  x += 0x7fffu + ((x >> 16) & 1u);          // round-to-nearest-even
  return (u16)(x >> 16);
}

static __device__ __forceinline__ void gload_lds16(const void* g, void* l){
  __builtin_amdgcn_global_load_lds((__attribute__((address_space(1))) void*)(void*)(g),
                                   (__attribute__((address_space(3))) void*)(l), 16, 0, 0);
}

// ---------------- converts ----------------

__global__ __launch_bounds__(256) void cvt_bf16(const float* __restrict__ in,
                                                u16* __restrict__ out, int n){
  int i = (blockIdx.x * 256 + threadIdx.x) * 8;
  const int stride = gridDim.x * 256 * 8;
  for (; i < n; i += stride){
    float4 a = *(const float4*)(in + i);
    float4 b = *(const float4*)(in + i + 4);
    uint4 o;
    o.x = (u32)f2bf(a.x) | ((u32)f2bf(a.y) << 16);
    o.y = (u32)f2bf(a.z) | ((u32)f2bf(a.w) << 16);
    o.z = (u32)f2bf(b.x) | ((u32)f2bf(b.y) << 16);
    o.w = (u32)f2bf(b.z) | ((u32)f2bf(b.w) << 16);
    *(uint4*)(out + i) = o;
  }
}

// in[R][C] fp32 -> out[C][R] bf16
__global__ __launch_bounds__(256) void transpose_cvt(const float* __restrict__ in,
                                                     u16* __restrict__ out, int R, int C){
  __shared__ float tile[32][33];
  const int bx = blockIdx.x * 32;   // along C
  const int by = blockIdx.y * 32;   // along R
  const int tx = threadIdx.x & 31, ty = threadIdx.x >> 5;   // 32 x 8
  #pragma unroll
  for (int i = 0; i < 32; i += 8)
    tile[ty + i][tx] = in[(size_t)(by + ty + i) * C + bx + tx];
  __syncthreads();
  #pragma unroll
  for (int i = 0; i < 32; i += 8)
    out[(size_t)(bx + ty + i) * R + by + tx] = f2bf(tile[tx][ty + i]);
}

// ---------------- GEMM: C[M,N] = A[M,K] * Bt[N,K]^T + bias ----------------
// 128x128 tile, BK=64, 4 waves (each 64x64), mfma_f32_16x16x32_bf16.
// LDS rows are 128B; content XOR-swizzled via pre-swizzled global source (G21).

template<int EPIL>   // 0: scatter to q/k/v [B,H,T,D] bf16; 1: fp32 [M,EMB] out
__global__ __launch_bounds__(256) void gemm_bf16(
    const u16* __restrict__ A,    // [M][1024] bf16
    const u16* __restrict__ Bt,   // [N][1024] bf16 (transposed weights)
    const float* __restrict__ bias, // [N]
    u16* __restrict__ obf,        // EPIL=0 dest (qkv base)
    float* __restrict__ of)       // EPIL=1 dest
{
  constexpr int K = 1024, BK = 64;
  __shared__ u16 As[128 * 64];
  __shared__ u16 Bs[128 * 64];
  const int tid = threadIdx.x, lane = tid & 63, wave = tid >> 6;
  const int m0 = blockIdx.y * 128, n0 = blockIdx.x * 128;
  const int wr = (wave >> 1) * 64, wc = (wave & 1) * 64;

  // staging: wave stages rows wave*32 + j*8 + (lane>>3); dest byte-in-row (lane&7)*16
  const int srow = lane >> 3;                                   // 0..7
  const int scol = ((((lane & 7) << 4) ^ (srow << 4)) >> 1);    // pre-swizzled src col (elems)
  const u16* ag = A  + (size_t)(m0 + wave * 32 + srow) * K + scol;
  const u16* bg = Bt + (size_t)(n0 + wave * 32 + srow) * K + scol;
  u16* al = &As[wave * 32 * 64];
  u16* bl = &Bs[wave * 32 * 64];

  f32x4 acc[4][4] = {};

  for (int kt = 0; kt < K / BK; ++kt){
    #pragma unroll
    for (int j = 0; j < 4; ++j){
      gload_lds16(ag + (size_t)j * 8 * K + kt * BK, al + j * 8 * 64);
      gload_lds16(bg + (size_t)j * 8 * K + kt * BK, bl + j * 8 * 64);
    }
    __syncthreads();
    #pragma unroll
    for (int ks = 0; ks < 2; ++ks){
      const int fr = lane & 15;
      const int colb = ((ks << 6) + ((lane >> 4) << 4)) ^ ((lane & 7) << 4); // byte in row
      bf16x8 af[4], bfr[4];
      #pragma unroll
      for (int mi = 0; mi < 4; ++mi)
        af[mi] = *(const bf16x8*)((const char*)As + (wr + mi * 16 + fr) * 128 + colb);
      #pragma unroll
      for (int ni = 0; ni < 4; ++ni)
        bfr[ni] = *(const bf16x8*)((const char*)Bs + (wc + ni * 16 + fr) * 128 + colb);
      #pragma unroll
      for (int mi = 0; mi < 4; ++mi)
        #pragma unroll
        for (int ni = 0; ni < 4; ++ni)
          acc[mi][ni] = __builtin_amdgcn_mfma_f32_16x16x32_bf16(af[mi], bfr[ni], acc[mi][ni], 0, 0, 0);
    }
    __syncthreads();
  }

  // epilogue: C row = (lane>>4)*4 + j, col = lane&15 (HW-verified layout)
  #pragma unroll
  for (int mi = 0; mi < 4; ++mi){
    const int rg = m0 + wr + mi * 16 + ((lane >> 4) << 2);
    #pragma unroll
    for (int ni = 0; ni < 4; ++ni){
      const int cg = n0 + wc + ni * 16 + (lane & 15);
      const float bs = bias[cg];
      if constexpr (EPIL == 0){
        const int which = cg >> 10, hm = cg & 1023;
        const int b = rg >> 11, t = rg & 2047;
        u16* dst = obf + (size_t)which * QKVSZ
                       + ((size_t)(b * NH + (hm >> 7)) * SEQ + t) * HD + (hm & 127);
        #pragma unroll
        for (int j = 0; j < 4; ++j)
          dst[(size_t)j * HD] = f2bf(acc[mi][ni][j] + bs);
      } else {
        #pragma unroll
        for (int j = 0; j < 4; ++j)
          of[(size_t)(rg + j) * EMB + cg] = acc[mi][ni][j] + bs;
      }
    }
  }
}

// ---------------- sliding-window attention ----------------
// block = (64-query tile) x (b,h). 4 waves; wave owns 16 q rows.
// keys span [q0-128, q0+64) = 3 chunks of 64. Two-pass softmax via fp32 S in LDS.

__global__ __launch_bounds__(256) void attn_kernel(
    const u16* __restrict__ QKVb, const float* __restrict__ gate, u16* __restrict__ Ao)
{
  __shared__ float S[64 * 196];     // padded rows (196 fp32) -> bank spread
  __shared__ u16 KV[128 * 72];      // K chunk [64][136-pad] or Vt [128][72-pad]
  const int tid = threadIdx.x, lane = tid & 63, wave = tid >> 6;
  const int q0 = blockIdx.x * 64;
  const int bh = blockIdx.y;
  const u16* Qg = QKVb + (size_t)bh * HSZ;
  const u16* Kg = QKVb + (size_t)QKVSZ + (size_t)bh * HSZ;
  const u16* Vg = QKVb + (size_t)2 * QKVSZ + (size_t)bh * HSZ;
  const int kstart = q0 - WIN;

  bf16x8 qf[4];
  {
    const u16* qp = Qg + (size_t)(q0 + wave * 16 + (lane & 15)) * HD + 8 * (lane >> 4);
    #pragma unroll
    for (int ks = 0; ks < 4; ++ks) qf[ks] = *(const bf16x8*)(qp + ks * 32);
  }
  const float scale = 0.08838834764831845f;   // 1/sqrt(128)

  for (int c = 0; c < 3; ++c){
    { // stage K chunk: KV[key][d], padded row = 136 elems
      const int keyl = tid >> 2;
      int krow = kstart + c * 64 + keyl;
      krow = min(max(krow, 0), SEQ - 1);
      const u16* kp = Kg + (size_t)krow * HD + (tid & 3) * 8;
      u16* ksh = &KV[keyl * 136 + (tid & 3) * 8];
      #pragma unroll
      for (int r = 0; r < 4; ++r)
        *(uint4*)(ksh + r * 32) = *(const uint4*)(kp + r * 32);
    }
    __syncthreads();
    f32x4 sacc[4] = {};
    #pragma unroll
    for (int ks = 0; ks < 4; ++ks){
      #pragma unroll
      for (int nf = 0; nf < 4; ++nf){
        bf16x8 kf = *(const bf16x8*)(&KV[(nf * 16 + (lane & 15)) * 136 + ks * 32 + 8 * (lane >> 4)]);
        sacc[nf] = __builtin_amdgcn_mfma_f32_16x16x32_bf16(qf[ks], kf, sacc[nf], 0, 0, 0);
      }
    }
    #pragma unroll
    for (int nf = 0; nf < 4; ++nf){
      const int kc = c * 64 + nf * 16 + (lane & 15);
      const int kg = kstart + kc;
      #pragma unroll
      for (int j = 0; j < 4; ++j){
        const int qr = wave * 16 + ((lane >> 4) << 2) + j;
        const int qg = q0 + qr;
        const bool ok = (kg >= 0) && (kg <= qg) && (qg - kg <= WIN);
        S[qr * 196 + kc] = ok ? sacc[nf][j] * scale : -1e30f;
      }
    }
    __syncthreads();
  }

  { // softmax: 4 lanes per row
    const int r = tid >> 2, sub = tid & 3;
    float4 v[12];
    float mx = -1e30f;
    #pragma unroll
    for (int i = 0; i < 12; ++i){
      v[i] = *(const float4*)(&S[r * 196 + (sub + 4 * i) * 4]);
      mx = fmaxf(mx, fmaxf(fmaxf(v[i].x, v[i].y), fmaxf(v[i].z, v[i].w)));
    }
    mx = fmaxf(mx, __shfl_xor(mx, 1));
    mx = fmaxf(mx, __shfl_xor(mx, 2));
    float sum = 0.f;
    #pragma unroll
    for (int i = 0; i < 12; ++i){
      v[i].x = __expf(v[i].x - mx); v[i].y = __expf(v[i].y - mx);
      v[i].z = __expf(v[i].z - mx); v[i].w = __expf(v[i].w - mx);
      sum += v[i].x + v[i].y + v[i].z + v[i].w;
    }
    sum += __shfl_xor(sum, 1);
    sum += __shfl_xor(sum, 2);
    const float inv = 1.0f / sum;
    #pragma unroll
    for (int i = 0; i < 12; ++i){
      v[i].x *= inv; v[i].y *= inv; v[i].z *= inv; v[i].w *= inv;
      *(float4*)(&S[r * 196 + (sub + 4 * i) * 4]) = v[i];
    }
  }
  __syncthreads();

  f32x4 oacc[8] = {};
  for (int c = 0; c < 3; ++c){
    { // stage V chunk transposed: KV[d][key], padded row = 72 elems
      const int keyl = tid & 63;
      int krow = kstart + c * 64 + keyl;
      krow = min(max(krow, 0), SEQ - 1);
      const u16* vp = Vg + (size_t)krow * HD + (tid >> 6) * 32;
      #pragma unroll
      for (int r2 = 0; r2 < 4; ++r2){
        u16x8 vv = *(const u16x8*)(vp + r2 * 8);
        const int dbase = (tid >> 6) * 32 + r2 * 8;
        #pragma unroll
        for (int j = 0; j < 8; ++j)
          KV[(dbase + j) * 72 + keyl] = vv[j];
      }
    }
    __syncthreads();
    #pragma unroll
    for (int ks = 0; ks < 2; ++ks){
      const float* sp = &S[(wave * 16 + (lane & 15)) * 196 + c * 64 + ks * 32 + 8 * (lane >> 4)];
      float4 p0 = *(const float4*)sp;
      float4 p1 = *(const float4*)(sp + 4);
      bf16x8 pf;
      pf[0] = (short)f2bf(p0.x); pf[1] = (short)f2bf(p0.y);
      pf[2] = (short)f2bf(p0.z); pf[3] = (short)f2bf(p0.w);
      pf[4] = (short)f2bf(p1.x); pf[5] = (short)f2bf(p1.y);
      pf[6] = (short)f2bf(p1.z); pf[7] = (short)f2bf(p1.w);
      #pragma unroll
      for (int nf = 0; nf < 8; ++nf){
        bf16x8 vf = *(const bf16x8*)(&KV[(nf * 16 + (lane & 15)) * 72 + ks * 32 + 8 * (lane >> 4)]);
        oacc[nf] = __builtin_amdgcn_mfma_f32_16x16x32_bf16(pf, vf, oacc[nf], 0, 0, 0);
      }
    }
    __syncthreads();
  }

  { // epilogue: apply gate, write bf16 [B,T,C]
    const int b = bh >> 3, h = bh & 7;
    #pragma unroll
    for (int nf = 0; nf < 8; ++nf){
      const int d = nf * 16 + (lane & 15);
      const float gv = gate[h * HD + d];
      #pragma unroll
      for (int j = 0; j < 4; ++j){
        const int t = q0 + wave * 16 + ((lane >> 4) << 2) + j;
        Ao[((size_t)(b * SEQ + t)) * EMB + h * HD + d] = f2bf(oacc[nf][j] * gv);
      }
    }
  }
}

// ---------------- launch ----------------

extern "C" void kernel_launch(void* const* d_in, const int* in_sizes, int n_in,
                              void* d_out, int out_size, void* d_ws, size_t ws_size,
                              hipStream_t stream)
{
  const float* x     = (const float*)d_in[0];
  const float* Wqkv  = (const float*)d_in[1];
  const float* bqkv  = (const float*)d_in[2];
  const float* Wproj = (const float*)d_in[3];
  const float* bproj = (const float*)d_in[4];
  const float* gate  = (const float*)d_in[5];
  float* out = (float*)d_out;

  u16* Xb   = (u16*)d_ws;                        // [4096][1024]
  u16* Wqt  = Xb   + (size_t)MTOT * EMB;         // [3072][1024]
  u16* Wpt  = Wqt  + (size_t)NQKV * EMB;         // [1024][1024]
  u16* QKVb = Wpt  + (size_t)EMB * EMB;          // 3 x [B,H,T,D]
  u16* Ao   = QKVb + (size_t)3 * QKVSZ;          // [4096][1024] gated attn out

  cvt_bf16<<<dim3(2048), dim3(256), 0, stream>>>(x, Xb, MTOT * EMB);
  transpose_cvt<<<dim3(NQKV / 32, EMB / 32), dim3(256), 0, stream>>>(Wqkv, Wqt, EMB, NQKV);
  transpose_cvt<<<dim3(EMB / 32, EMB / 32), dim3(256), 0, stream>>>(Wproj, Wpt, EMB, EMB);

  gemm_bf16<0><<<dim3(NQKV / 128, MTOT / 128), dim3(256), 0, stream>>>(
      Xb, Wqt, bqkv, QKVb, (float*)nullptr);

  attn_kernel<<<dim3(SEQ / 64, NB * NH), dim3(256), 0, stream>>>(QKVb, gate, Ao);

  gemm_bf16<1><<<dim3(EMB / 128, MTOT / 128), dim3(256), 0, stream>>>(
      Ao, Wpt, bproj, (u16*)nullptr, out);
}